// Round 16
// baseline (196.918 us; speedup 1.0000x reference)
//
#include <hip/hip_runtime.h>
#include <hip/hip_bf16.h>
#include <cstdint>

#define B 32
#define L 512
#define T 2048
#define M 80
#define KDIM 160

#define NEG_INF (-1e30f)
#define LOG_2PI 1.8378770664093453f

typedef uint32_t u32;
typedef unsigned short u16;
typedef u16 u16x8 __attribute__((ext_vector_type(8)));
typedef short bf16x8 __attribute__((ext_vector_type(8)));
typedef float f32x4 __attribute__((ext_vector_type(4)));
typedef u32 u32x2 __attribute__((ext_vector_type(2)));

// robust to harness passing lengths as int32 or int64 (values are small positive;
// if int64, word[1] == high word of elem0 == 0; if int32, word[1] in [64,2048] != 0)
__device__ __forceinline__ int get_len(const int* __restrict__ p, int b) {
  return (p[1] == 0) ? p[2 * b] : p[b];
}

__device__ __forceinline__ u16 f2bf(float f) {
  __hip_bfloat16 h = __float2bfloat16(f);
  return *(u16*)&h;
}

// ---------------- prep: Wfrag[b][kc][l][8] (bf16 B-fragments), bias[b][l] --------
__global__ __launch_bounds__(256) void prep_kernel(const float* __restrict__ mu_sigma,
                                                   u16* __restrict__ Wfrag,
                                                   float* __restrict__ biasv) {
  int gid = blockIdx.x * 256 + threadIdx.x;  // b*L + l
  if (gid >= B * L) return;
  int b = gid >> 9;
  int l = gid & (L - 1);
  const float* row = mu_sigma + (size_t)gid * (2 * M);
  float acc_a = 0.f, acc_ls = 0.f;
#pragma unroll 2
  for (int g = 0; g < 10; ++g) {
    u16x8 wsq, wli;
#pragma unroll
    for (int j = 0; j < 8; ++j) {
      float mu = row[g * 8 + j];
      float ls = row[M + g * 8 + j];
      float iv = expf(-2.f * ls);
      acc_a += mu * mu * iv;
      acc_ls += ls;
      wsq[j] = f2bf(-0.5f * iv);
      wli[j] = f2bf(mu * iv);
    }
    *(u16x8*)(Wfrag + ((size_t)(b * 20 + g) * L + l) * 8) = wsq;
    *(u16x8*)(Wfrag + ((size_t)(b * 20 + 10 + g) * L + l) * 8) = wli;
  }
  biasv[gid] = -0.5f * acc_a - (0.5f * (float)M * LOG_2PI + 0.5f * acc_ls);
}

// ---------------- xprep: Xfrag[b][kc][t][8] (bf16 A-fragments) ----------------
__global__ __launch_bounds__(256) void xprep_kernel(const float* __restrict__ melspec,
                                                    u16* __restrict__ Xfrag) {
  int gid = blockIdx.x * 256 + threadIdx.x;  // (b*10 + mg)*T + t
  int t = gid & (T - 1);
  int rest = gid >> 11;
  int mg = rest % 10;
  int b = rest / 10;
  u16x8 sq, li;
#pragma unroll
  for (int j = 0; j < 8; ++j) {
    float xv = melspec[((size_t)b * M + mg * 8 + j) * T + t];
    sq[j] = f2bf(xv * xv);
    li[j] = f2bf(xv);
  }
  *(u16x8*)(Xfrag + ((size_t)(b * 20 + mg) * T + t) * 8) = sq;
  *(u16x8*)(Xfrag + ((size_t)(b * 20 + 10 + mg) * T + t) * 8) = li;
}

// ---------------- gemm (MFMA): logpT[b][t][l] bf16 = bias + sum_k X*W ----------
__global__ __launch_bounds__(256) void gemm_logp(const u16* __restrict__ Xfrag,
                                                 const u16* __restrict__ Wfrag,
                                                 const float* __restrict__ biasv,
                                                 const int* __restrict__ mel_len,
                                                 const int* __restrict__ text_len,
                                                 u16* __restrict__ logpT,
                                                 int t_begin, int tc) {
  int b = blockIdx.z;
  int t0 = t_begin + blockIdx.x * 64;
  int l0 = blockIdx.y * 128;
  if (t0 >= get_len(mel_len, b)) return;
  if (l0 >= get_len(text_len, b)) return;

  int tid = threadIdx.x;
  int wave = tid >> 6, lane = tid & 63;
  int wt = wave >> 1, wl = wave & 1;
  int mbase = t0 + wt * 32;
  int nbase = l0 + wl * 64;
  int l16 = lane & 15, khalf = lane >> 4;

  const bf16x8* Xp = (const bf16x8*)Xfrag;
  const bf16x8* Wp = (const bf16x8*)Wfrag;

  f32x4 acc[2][4];
#pragma unroll
  for (int i = 0; i < 2; ++i)
#pragma unroll
    for (int j = 0; j < 4; ++j) acc[i][j] = (f32x4){0.f, 0.f, 0.f, 0.f};

#pragma unroll
  for (int ks = 0; ks < 5; ++ks) {
    int kc = ks * 4 + khalf;
    size_t xb = (size_t)(b * 20 + kc) * T;
    size_t wb = (size_t)(b * 20 + kc) * L;
    bf16x8 a0 = Xp[xb + mbase + l16];
    bf16x8 a1 = Xp[xb + mbase + 16 + l16];
    bf16x8 b0 = Wp[wb + nbase + l16];
    bf16x8 b1 = Wp[wb + nbase + 16 + l16];
    bf16x8 b2 = Wp[wb + nbase + 32 + l16];
    bf16x8 b3 = Wp[wb + nbase + 48 + l16];
    acc[0][0] = __builtin_amdgcn_mfma_f32_16x16x32_bf16(a0, b0, acc[0][0], 0, 0, 0);
    acc[0][1] = __builtin_amdgcn_mfma_f32_16x16x32_bf16(a0, b1, acc[0][1], 0, 0, 0);
    acc[0][2] = __builtin_amdgcn_mfma_f32_16x16x32_bf16(a0, b2, acc[0][2], 0, 0, 0);
    acc[0][3] = __builtin_amdgcn_mfma_f32_16x16x32_bf16(a0, b3, acc[0][3], 0, 0, 0);
    acc[1][0] = __builtin_amdgcn_mfma_f32_16x16x32_bf16(a1, b0, acc[1][0], 0, 0, 0);
    acc[1][1] = __builtin_amdgcn_mfma_f32_16x16x32_bf16(a1, b1, acc[1][1], 0, 0, 0);
    acc[1][2] = __builtin_amdgcn_mfma_f32_16x16x32_bf16(a1, b2, acc[1][2], 0, 0, 0);
    acc[1][3] = __builtin_amdgcn_mfma_f32_16x16x32_bf16(a1, b3, acc[1][3], 0, 0, 0);
  }

  // epilogue: C/D map col = lane&15, row = khalf*4 + r  [verified m89/m91]
  int rbase = khalf * 4;
#pragma unroll
  for (int j = 0; j < 4; ++j) {
    int colL = nbase + j * 16 + l16;
    float bias = biasv[b * L + colL];
#pragma unroll
    for (int i = 0; i < 2; ++i) {
#pragma unroll
      for (int r = 0; r < 4; ++r) {
        int t = mbase + i * 16 + rbase + r;
        logpT[((size_t)b * tc + (t - t_begin)) * L + colL] = f2bf(acc[i][j][r] + bias);
      }
    }
  }
}

// ---------------- scan: 2 batches/block, 4 sub-waves each, halo max-plus --------
// 16 blocks x 512 threads: waves 0-3 = batch 2*bid, waves 4-7 = batch 2*bid+1.
// 2 waves/SIMD -> batch A's lgkm/barrier/DMA stalls filled by batch B's VALU
// (R15 plateau diagnosis: 1 wave/SIMD left ~55% of active-CU time stalled).
// Per batch: sub-wave sw spans cols [128sw-128, 128sw+128) (4 cols/lane, one
// ds_read_b64/step), owns top 128; 128-col halo = 128-step staleness budget,
// refreshed every 32-row phase. Raw s_barrier + per-wave counted vmcnt(8) (DMA
// pipeline survives barriers - R14). Shared phase count = max over the pair;
// finished batch's waves keep hitting barriers with compute guarded off.
#define SROWS 32

#define VMW(n)                                             \
  do {                                                     \
    asm volatile("s_waitcnt vmcnt(" #n ")" ::: "memory");  \
    __builtin_amdgcn_sched_barrier(0);                     \
  } while (0)
#define LGKMC(n)                                           \
  do {                                                     \
    asm volatile("s_waitcnt lgkmcnt(" #n ")" ::: "memory");\
    __builtin_amdgcn_sched_barrier(0);                     \
  } while (0)
#define BAR()                                              \
  do {                                                     \
    asm volatile("" ::: "memory");                         \
    __builtin_amdgcn_s_barrier();                          \
    asm volatile("" ::: "memory");                         \
  } while (0)
#define RD64(dst, addr, imm) \
  asm volatile("ds_read_b64 %0, %1 offset:%c2" : "=v"(dst) : "v"(addr), "i"(imm))
#define RD4(P, base_)                 \
  do {                                \
    RD64(P##0, ringA, (base_));       \
    RD64(P##1, ringA, (base_) + 1024);\
    RD64(P##2, ringA, (base_) + 2048);\
    RD64(P##3, ringA, (base_) + 3072);\
  } while (0)
#define S4(P)                                     \
  do { stepv(P##0); stepv(P##1); stepv(P##2); stepv(P##3); } while (0)

__device__ __forceinline__ float dpp_shr1_neginf(float x) {
  int r = __builtin_amdgcn_update_dpp(__float_as_int(NEG_INF), __float_as_int(x),
                                      0x138, 0xf, 0xf, false);  // wave_shr:1
  return __int_as_float(r);
}

__global__ __launch_bounds__(512, 1) void scan_kernel(const u16* __restrict__ logpT,
                                                      const int* __restrict__ mel_len,
                                                      const int* __restrict__ text_len,
                                                      float* __restrict__ carry_ws,
                                                      float* __restrict__ la_ws,
                                                      int t_begin, int tc) {
  __shared__ u16 ring[2][2][SROWS][L];  // [slot][batch][row][col] 128 KB
  __shared__ float smem[2][2][L];       // [par][batch][col] 8 KB halo exchange
  int tid = threadIdx.x;
  int wave = tid >> 6;
  int lane = tid & 63;
  int sw = wave & 3;    // sub-wave within batch (R15's "wave")
  int bb = wave >> 2;   // which batch of the pair
  int b = blockIdx.x * 2 + bb;
  int ml = get_len(mel_len, b);
  int tl = get_len(text_len, b);
  int ml_pair = max(ml, get_len(mel_len, blockIdx.x * 2 + (bb ^ 1)));
  const u16* base0 = logpT + (size_t)b * tc * L;
  float* cws = carry_ws + b * L;
  int col_lane = 128 * sw - 128 + 4 * lane;   // first of 4 cols (may be <0)
  int cl = (col_lane < 0) ? 0 : col_lane;     // clamped for loads
  bool owner = (lane >= 32);                  // owns cols 128sw..128sw+127

  float c0 = NEG_INF, c1 = NEG_INF, c2 = NEG_INF, c3 = NEG_INF;
  int tstart;
  if (t_begin == 0) {
    if (sw == 0 && lane == 32) c0 = __uint_as_float((u32)base0[0] << 16);
    tstart = 1;
  } else {
    float4 v = *(const float4*)(cws + cl);
    c0 = v.x; c1 = v.y; c2 = v.z; c3 = v.w;
    if (col_lane < 0) { c0 = NEG_INF; c1 = NEG_INF; c2 = NEG_INF; c3 = NEG_INF; }
    tstart = t_begin;
  }

  int tstop = min(t_begin + tc, ml);          // this batch
  int tstop_sh = min(t_begin + tc, ml_pair);  // shared loop bound (pair max)
  int tlast = (tstop - 1 > t_begin) ? (tstop - 1) : t_begin;  // safe clamp row

  auto stepv = [&](u32x2 v) {
    float p = dpp_shr1_neginf(c3);  // lane-1's old c3; lane0 <- NEG_INF
    float f0 = __uint_as_float(v.x << 16);
    float f1 = __uint_as_float(v.x & 0xFFFF0000u);
    float f2 = __uint_as_float(v.y << 16);
    float f3 = __uint_as_float(v.y & 0xFFFF0000u);
    c3 = fmaxf(c3, c2) + f3;
    c2 = fmaxf(c2, c1) + f2;
    c1 = fmaxf(c1, c0) + f1;
    c0 = fmaxf(c0, p) + f0;
  };

  int nrows_sh = tstop_sh - tstart;
  if (nrows_sh > 0) {
    int np = (nrows_sh + SROWS - 1) / SROWS;  // shared phase count

    auto stage = [&](int ph) -> bool {  // each wave DMAs its own 8 rows
      if (ph >= np) return false;
      int pr = tstart + ph * SROWS + 8 * sw;
      u16* d0 = &ring[ph & 1][bb][8 * sw][0];
#pragma unroll
      for (int j = 0; j < 8; ++j) {
        int t = pr + j;
        t = (t > tlast) ? tlast : t;  // clamp; dup rows unread
        const u16* s = base0 + (size_t)(t - t_begin) * L + lane * 8;
        __builtin_amdgcn_global_load_lds(
            (const __attribute__((address_space(1))) void*)s,
            (__attribute__((address_space(3))) void*)(d0 + (size_t)j * L + lane * 8),
            16, 0, 0);
      }
      return true;
    };

    stage(0);
    for (int k = 0; k < np; ++k) {
      BAR();  // slot (k+1)&1 free (phase k-1 consumed by all waves)
      bool nx = stage(k + 1);
      if (nx) VMW(8); else VMW(0);  // own phase-k loads landed
      BAR();  // all waves' phase-k rows in LDS; smem[(k-1)&1] visible
      int pstart = tstart + k * SROWS;
      int rem = tstop - pstart;  // per-batch; <=0 -> batch finished
      if (rem > 0) {
        if (k > 0 && sw > 0 && lane < 32) {  // exact halo refresh
          float4 h = *(const float4*)&smem[(k - 1) & 1][bb][col_lane];
          c0 = h.x; c1 = h.y; c2 = h.z; c3 = h.w;
        }
        if (rem > SROWS) rem = SROWS;
        u32 ringA = (u32)(uintptr_t)(__attribute__((address_space(3)))
                                     u16*)(&ring[k & 1][bb][0][0]) +
                    2u * (u32)cl;
        if (rem == SROWS) {
          u32x2 qA0, qA1, qA2, qA3, qB0, qB1, qB2, qB3;
          RD4(qA, 0);     RD4(qB, 4096);
          LGKMC(4); S4(qA); RD4(qA, 8192);
          LGKMC(4); S4(qB); RD4(qB, 12288);
          LGKMC(4); S4(qA); RD4(qA, 16384);
          LGKMC(4); S4(qB); RD4(qB, 20480);
          LGKMC(4); S4(qA); RD4(qA, 24576);
          LGKMC(4); S4(qB); RD4(qB, 28672);
          LGKMC(4); S4(qA);
          LGKMC(0); S4(qB);
        } else {
          const char* rp = (const char*)(&ring[k & 1][bb][0][0]) + 2 * cl;
          for (int r = 0; r < rem; ++r) {
            u32x2 v = *(const u32x2*)(rp + (size_t)r * (L * 2));
            stepv(v);
          }
        }
        if (owner) {  // publish owned cols for next phase's halo refresh
          *(float4*)&smem[k & 1][bb][col_lane] = make_float4(c0, c1, c2, c3);
        }
        LGKMC(0);  // ds_write visible before next barrier
      }
    }
  }

  // persist carry (owned cols only)
  if (owner) *(float4*)(cws + col_lane) = make_float4(c0, c1, c2, c3);

  if (t_begin + tc >= T) {  // last chunk: la[b] = alpha[ml-1][tl-1]
    int li = tl - 1;
    int w_own = li >> 7;
    if (sw == w_own) {
      int sub = li & 3;
      float v = (sub == 0) ? c0 : (sub == 1) ? c1 : (sub == 2) ? c2 : c3;
      float lav = __shfl(v, 32 + ((li & 127) >> 2));
      if (lane == 0) la_ws[b] = lav;
    }
  }
}

__global__ __launch_bounds__(64) void reduce_kernel(const float* __restrict__ la_ws,
                                                    float* __restrict__ out) {
  int lane = threadIdx.x;
  float v = (lane < B) ? la_ws[lane] : 0.f;
#pragma unroll
  for (int s = 32; s > 0; s >>= 1) v += __shfl_down(v, s);
  if (lane == 0) out[0] = -v * (1.0f / (float)B);
}

extern "C" void kernel_launch(void* const* d_in, const int* in_sizes, int n_in,
                              void* d_out, int out_size, void* d_ws, size_t ws_size,
                              hipStream_t stream) {
  const float* mu_sigma = (const float*)d_in[0];
  const float* melspec  = (const float*)d_in[1];
  const int*   text_len = (const int*)d_in[2];
  const int*   mel_len  = (const int*)d_in[3];
  float* out = (float*)d_out;

  char* ws = (char*)d_ws;
  size_t off = 0;
  u16* Wfrag = (u16*)(ws + off);         off += (size_t)B * KDIM * L * 2;      // 5.2 MB
  float* biasv = (float*)(ws + off);     off += (size_t)B * L * 4;
  float* carry_ws = (float*)(ws + off);  off += (size_t)B * L * 4;
  float* la_ws = (float*)(ws + off);     off += 256;
  u16* Xfrag = (u16*)(ws + off);         off += (size_t)B * KDIM * T * 2;      // 21 MB
  u16* logpT = (u16*)(ws + off);
  size_t avail = (ws_size > off) ? (ws_size - off) : 0;
  size_t per_t = (size_t)B * L * 2;  // bytes per t-slice across all b (bf16)
  long long tcl = (long long)(avail / per_t);
  int Tc = (tcl > T) ? T : (int)tcl;
  Tc &= ~63;
  if (Tc < 64) return;  // insufficient workspace (not expected)

  prep_kernel<<<dim3((B * L + 255) / 256), 256, 0, stream>>>(mu_sigma, Wfrag, biasv);
  xprep_kernel<<<dim3((B * 10 * T) / 256), 256, 0, stream>>>(melspec, Xfrag);

  for (int t_begin = 0; t_begin < T; t_begin += Tc) {
    int tc = (T - t_begin < Tc) ? (T - t_begin) : Tc;
    dim3 grid(tc / 64, L / 128, B);
    gemm_logp<<<grid, 256, 0, stream>>>(Xfrag, Wfrag, biasv, mel_len, text_len,
                                        logpT, t_begin, tc);
    scan_kernel<<<dim3(B / 2), 512, 0, stream>>>(logpT, mel_len, text_len, carry_ws,
                                                 la_ws, t_begin, tc);
  }
  reduce_kernel<<<1, 64, 0, stream>>>(la_ws, out);
}